// Round 1
// baseline (359.993 us; speedup 1.0000x reference)
//
#include <hip/hip_runtime.h>
#include <cstdint>
#include <cstddef>

// Problem constants
// B=16, N=300, D=256, HEADS=8, HD=32, L=8500, TP=16, HID=512
// SPATIAL = (80,80),(40,40),(20,20),(10,10); starts 0,6400,8000,8400

__device__ __forceinline__ unsigned short f2bf(float f) {
  unsigned int u = __float_as_uint(f);
  u = (u + 0x7fffu + ((u >> 16) & 1u)) >> 16;   // round-to-nearest-even
  return (unsigned short)u;
}
__device__ __forceinline__ float bf2f(unsigned short b) {
  return __uint_as_float(((unsigned int)b) << 16);
}

// ---------------------------------------------------------------------------
// Generic tiled SGEMM: C(M,N) = A(M,K) @ W(N,K)^T + bias(N)
// Requires M%64==0, N%64==0, K%BK==0 (true for every call here).
// 256 threads, 64x64 tile, 4x4 per-thread microtile.
// ---------------------------------------------------------------------------
template <int BK>
__global__ __launch_bounds__(256) void gemm_bias(
    const float* __restrict__ A, const float* __restrict__ W,
    const float* __restrict__ bias, float* __restrict__ C,
    int M, int N, int K)
{
  __shared__ float As[BK][68];  // [k][m], +4 pad: keeps float4 reads 16B-aligned, spreads banks
  __shared__ float Ws[BK][68];  // [k][n]
  const int tid = threadIdx.x;
  const int tx = tid & 15;       // 16 thread-cols * 4 = 64
  const int ty = tid >> 4;       // 16 thread-rows * 4 = 64
  const int row0 = blockIdx.y * 64;
  const int col0 = blockIdx.x * 64;

  float acc[4][4] = {};

  for (int k0 = 0; k0 < K; k0 += BK) {
#pragma unroll
    for (int i = 0; i < (64 * BK) / 256; ++i) {
      int idx = tid + i * 256;
      int m = idx / BK, k = idx % BK;
      As[k][m] = A[(size_t)(row0 + m) * K + k0 + k];
      Ws[k][m] = W[(size_t)(col0 + m) * K + k0 + k];
    }
    __syncthreads();
#pragma unroll
    for (int k = 0; k < BK; ++k) {
      float a4[4], b4[4];
      *(float4*)a4 = *(const float4*)&As[k][ty * 4];
      *(float4*)b4 = *(const float4*)&Ws[k][tx * 4];
#pragma unroll
      for (int i = 0; i < 4; ++i)
#pragma unroll
        for (int j = 0; j < 4; ++j)
          acc[i][j] = fmaf(a4[i], b4[j], acc[i][j]);
    }
    __syncthreads();
  }

#pragma unroll
  for (int i = 0; i < 4; ++i) {
    int r = row0 + ty * 4 + i;
    int c = col0 + tx * 4;
    float4 o;
    o.x = acc[i][0] + bias[c + 0];
    o.y = acc[i][1] + bias[c + 1];
    o.z = acc[i][2] + bias[c + 2];
    o.w = acc[i][3] + bias[c + 3];
    *(float4*)&C[(size_t)r * N + c] = o;
  }
}

// ---------------------------------------------------------------------------
// Fused self-attention. qkv: (B,N,3,H,32) f32. sa out: (B,N,H*32) f32.
// grid = (4 q-chunks of 75, B*H). 256 threads = 4 waves; wave handles ~19 q.
// K,V staged bf16 in LDS; scores/accum f32; full-wave shuffle softmax.
// ---------------------------------------------------------------------------
__global__ __launch_bounds__(256) void attn_fused(
    const float* __restrict__ qkv, float* __restrict__ sa)
{
  __shared__ unsigned short Kt[32][304];   // [c][j] bf16
  __shared__ unsigned short Vb[300][32];   // [j][c] bf16
  __shared__ float Qs[75][32];
  __shared__ float pbuf[4][300];

  const int bh = blockIdx.y, b = bh >> 3, h = bh & 7;
  const int q0 = blockIdx.x * 75;
  const int t = threadIdx.x, wave = t >> 6, lane = t & 63;
  const size_t base = (size_t)b * 300 * 768 + (size_t)h * 32;

  for (int i = t; i < 300 * 32; i += 256) {
    int j = i >> 5, c = i & 31;
    Kt[c][j] = f2bf(qkv[base + (size_t)j * 768 + 256 + c]);
    Vb[j][c] = f2bf(qkv[base + (size_t)j * 768 + 512 + c]);
  }
  for (int i = t; i < 75 * 32; i += 256) {
    int q = i >> 5, c = i & 31;
    Qs[q][c] = qkv[base + (size_t)(q0 + q) * 768 + c];
  }
  __syncthreads();

  const int qs = wave * 19;
  const int qe = min(qs + 19, 75);
  const int c32 = lane & 31, half = lane >> 5;
  const float scale = 0.17677669529663687f;  // 1/sqrt(32)

  for (int q = qs; q < qe; ++q) {
    float qreg[32];
#pragma unroll
    for (int c = 0; c < 32; ++c) qreg[c] = Qs[q][c];

    float s[5];
#pragma unroll
    for (int i = 0; i < 5; ++i) {
      int j = lane + 64 * i;
      if (j < 300) {
        float a = 0.f;
#pragma unroll
        for (int c = 0; c < 32; ++c) a = fmaf(qreg[c], bf2f(Kt[c][j]), a);
        s[i] = a * scale;
      } else {
        s[i] = -3.0e38f;
      }
    }
    float m = fmaxf(fmaxf(fmaxf(s[0], s[1]), fmaxf(s[2], s[3])), s[4]);
#pragma unroll
    for (int o = 32; o; o >>= 1) m = fmaxf(m, __shfl_xor(m, o));
    float e[5], sum = 0.f;
#pragma unroll
    for (int i = 0; i < 5; ++i) {
      e[i] = (lane + 64 * i < 300) ? __expf(s[i] - m) : 0.f;
      sum += e[i];
    }
#pragma unroll
    for (int o = 32; o; o >>= 1) sum += __shfl_xor(sum, o);
    float inv = 1.f / sum;
#pragma unroll
    for (int i = 0; i < 5; ++i) {
      int j = lane + 64 * i;
      if (j < 300) pbuf[wave][j] = e[i] * inv;
    }
    asm volatile("s_waitcnt lgkmcnt(0)" ::: "memory");  // cross-lane LDS RAW within wave

    float acc = 0.f;
    const int jb = half * 150;
#pragma unroll 2
    for (int jj = 0; jj < 150; ++jj) {
      int j = jb + jj;
      acc = fmaf(pbuf[wave][j], bf2f(Vb[j][c32]), acc);
    }
    acc += __shfl_xor(acc, 32);
    if (lane < 32)
      sa[((size_t)b * 300 + q0 + q) * 256 + h * 32 + c32] = acc;
  }
}

// ---------------------------------------------------------------------------
// out = rmsnorm(a + b [clipped], w)   rows=4800, D=256, one block per row
// ---------------------------------------------------------------------------
__global__ __launch_bounds__(256) void add_rmsnorm(
    const float* __restrict__ a, const float* __restrict__ bsrc,
    const float* __restrict__ w, float* __restrict__ out, int clip)
{
  __shared__ float red[4];
  const int row = blockIdx.x, t = threadIdx.x;
  const size_t idx = (size_t)row * 256 + t;
  float v = a[idx] + bsrc[idx];
  if (clip) v = fminf(fmaxf(v, -65504.f), 65504.f);
  float s = v * v;
#pragma unroll
  for (int o = 32; o; o >>= 1) s += __shfl_xor(s, o);
  if ((t & 63) == 0) red[t >> 6] = s;
  __syncthreads();
  float tot = red[0] + red[1] + red[2] + red[3];
  out[idx] = v * rsqrtf(tot * (1.0f / 256.0f) + 1e-6f) * w[t];
}

// ---------------------------------------------------------------------------
// hid = silu(h[:, :512]) * h[:, 512:]
// ---------------------------------------------------------------------------
__global__ __launch_bounds__(256) void swiglu_k(
    const float* __restrict__ h, float* __restrict__ hid)
{
  size_t i = (size_t)blockIdx.x * 256 + threadIdx.x;  // < 4800*512
  int row = (int)(i >> 9), c = (int)(i & 511);
  float a = h[(size_t)row * 1024 + c];
  float g = h[(size_t)row * 1024 + 512 + c];
  hid[i] = a / (1.f + __expf(-a)) * g;
}

// ---------------------------------------------------------------------------
// Deformable sampling. One block per (b,n). Computes aw softmax + sample locs
// in LDS, then each thread = (head, channel) accumulates 16 points x 4 corners.
// Gathers: 32 consecutive channels -> 128B coalesced per half-wave.
// ---------------------------------------------------------------------------
__global__ __launch_bounds__(256) void deform_k(
    const float* __restrict__ memory, const float* __restrict__ refp,
    const float* __restrict__ OFF, const float* __restrict__ AW,
    float* __restrict__ ca)
{
  __shared__ float locx[8][16], locy[8][16], wgt[8][16];
  const int bn = blockIdx.x, b = bn / 300, t = threadIdx.x;

  if (t < 128) {
    int h = t >> 4, p = t & 15;
    float cx = refp[(size_t)bn * 4 + 0], cy = refp[(size_t)bn * 4 + 1];
    float rw = refp[(size_t)bn * 4 + 2], rh = refp[(size_t)bn * 4 + 3];
    float ox = OFF[(size_t)bn * 256 + h * 32 + p * 2 + 0];
    float oy = OFF[(size_t)bn * 256 + h * 32 + p * 2 + 1];
    // loc = ref_xy + off * (1/NP) * ref_wh * 0.5
    locx[h][p] = cx + ox * 0.125f * rw;
    locy[h][p] = cy + oy * 0.125f * rh;
    float av = AW[(size_t)bn * 128 + t];
    float mx = av;
#pragma unroll
    for (int o = 8; o; o >>= 1) mx = fmaxf(mx, __shfl_xor(mx, o));
    float e = __expf(av - mx);
    float ssum = e;
#pragma unroll
    for (int o = 8; o; o >>= 1) ssum += __shfl_xor(ssum, o);
    wgt[h][p] = e / ssum;
  }
  __syncthreads();

  const int h = t >> 5, hd = t & 31;
  const float* mb = memory + (size_t)b * 8500 * 256 + h * 32 + hd;
  float acc = 0.f;
#pragma unroll
  for (int p = 0; p < 16; ++p) {
    const int HWs[4] = {80, 40, 20, 10};
    const int Sts[4] = {0, 6400, 8000, 8400};
    const int li = p >> 2;
    const int Hh = HWs[li], Ww = HWs[li], st = Sts[li];
    float x = locx[h][p] * (float)Ww - 0.5f;
    float y = locy[h][p] * (float)Hh - 0.5f;
    float x0f = floorf(x), y0f = floorf(y);
    float dx = x - x0f, dy = y - y0f;
    int x0 = (int)x0f, y0 = (int)y0f;
    float awp = wgt[h][p];
#pragma unroll
    for (int cc = 0; cc < 4; ++cc) {
      int xi = x0 + (cc & 1), yi = y0 + (cc >> 1);
      float wc = ((cc & 1) ? dx : 1.f - dx) * ((cc >> 1) ? dy : 1.f - dy);
      bool valid = (xi >= 0) && (xi < Ww) && (yi >= 0) && (yi < Hh);
      int xc = xi < 0 ? 0 : (xi >= Ww ? Ww - 1 : xi);
      int yc = yi < 0 ? 0 : (yi >= Hh ? Hh - 1 : yi);
      float g = mb[(size_t)(st + yc * Ww + xc) * 256];
      acc += g * (valid ? wc * awp : 0.f);
    }
  }
  ca[(size_t)bn * 256 + t] = acc;
}

// ---------------------------------------------------------------------------
extern "C" void kernel_launch(void* const* d_in, const int* in_sizes, int n_in,
                              void* d_out, int out_size, void* d_ws, size_t ws_size,
                              hipStream_t stream)
{
  (void)in_sizes; (void)n_in; (void)out_size; (void)ws_size;
  const float* target  = (const float*)d_in[0];
  const float* refp    = (const float*)d_in[1];
  const float* memory  = (const float*)d_in[2];
  const float* qkv_w   = (const float*)d_in[3];
  const float* qkv_b   = (const float*)d_in[4];
  const float* out_w   = (const float*)d_in[5];
  const float* out_b   = (const float*)d_in[6];
  const float* norm1_w = (const float*)d_in[7];
  const float* off_w   = (const float*)d_in[8];
  const float* off_b   = (const float*)d_in[9];
  const float* aw_w    = (const float*)d_in[10];
  const float* aw_b    = (const float*)d_in[11];
  const float* cout_w  = (const float*)d_in[12];
  const float* cout_b  = (const float*)d_in[13];
  const float* norm2_w = (const float*)d_in[14];
  const float* w13     = (const float*)d_in[15];
  const float* w13_b   = (const float*)d_in[16];
  const float* w2      = (const float*)d_in[17];
  const float* w2_b    = (const float*)d_in[18];
  const float* norm3_w = (const float*)d_in[19];
  float* out = (float*)d_out;

  float* ws  = (float*)d_ws;
  float* QKV = ws;                     // 4800*768
  float* SA  = QKV + 4800 * 768;       // 4800*256
  float* T1  = SA  + 4800 * 256;       // 4800*256 (reused 3x)
  float* X   = T1  + 4800 * 256;       // 4800*256
  float* OF  = X   + 4800 * 256;       // 4800*256
  float* AWb = OF  + 4800 * 256;       // 4800*128
  float* CA  = AWb + 4800 * 128;       // 4800*256
  float* X2  = CA  + 4800 * 256;       // 4800*256
  float* Hb  = X2  + 4800 * 256;       // 4800*1024
  float* HID = Hb  + 4800 * 1024;      // 4800*512
  // total: 19,046,400 floats = 76.2 MB

  dim3 blk(256);

  // 1. qkv = target @ qkv_w^T + qkv_b    (4800 x 768, K=256)
  gemm_bias<32><<<dim3(12, 75), blk, 0, stream>>>(target, qkv_w, qkv_b, QKV, 4800, 768, 256);
  // 2. self-attention -> SA (B,N,H*32)
  attn_fused<<<dim3(4, 128), blk, 0, stream>>>(QKV, SA);
  // 3. out proj
  gemm_bias<32><<<dim3(4, 75), blk, 0, stream>>>(SA, out_w, out_b, T1, 4800, 256, 256);
  // 4. x = rmsnorm(target + T1, norm1_w)
  add_rmsnorm<<<4800, blk, 0, stream>>>(target, T1, norm1_w, X, 0);
  // 5. offsets / attention-weight GEMMs
  gemm_bias<32><<<dim3(4, 75), blk, 0, stream>>>(X, off_w, off_b, OF, 4800, 256, 256);
  gemm_bias<32><<<dim3(2, 75), blk, 0, stream>>>(X, aw_w, aw_b, AWb, 4800, 128, 256);
  // 6. deformable sampling (fuses aw softmax + loc computation)
  deform_k<<<4800, blk, 0, stream>>>(memory, refp, OF, AWb, CA);
  // 7. cross-attn out proj
  gemm_bias<32><<<dim3(4, 75), blk, 0, stream>>>(CA, cout_w, cout_b, T1, 4800, 256, 256);
  // 8. x2 = rmsnorm(x + T1, norm2_w)
  add_rmsnorm<<<4800, blk, 0, stream>>>(X, T1, norm2_w, X2, 0);
  // 9. FFN
  gemm_bias<32><<<dim3(16, 75), blk, 0, stream>>>(X2, w13, w13_b, Hb, 4800, 1024, 256);
  swiglu_k<<<9600, blk, 0, stream>>>(Hb, HID);
  gemm_bias<32><<<dim3(4, 75), blk, 0, stream>>>(HID, w2, w2_b, T1, 4800, 256, 512);
  // 10. out = rmsnorm(clip(x2 + T1), norm3_w)
  add_rmsnorm<<<4800, blk, 0, stream>>>(X2, T1, norm3_w, out, 1);
}

// Round 2
// 262.894 us; speedup vs baseline: 1.3693x; 1.3693x over previous
//
#include <hip/hip_runtime.h>
#include <cstdint>
#include <cstddef>

// Problem constants
// B=16, N=300, D=256, HEADS=8, HD=32, L=8500, TP=16, HID=512
// SPATIAL = (80,80),(40,40),(20,20),(10,10); starts 0,6400,8000,8400

typedef __attribute__((ext_vector_type(8))) short bf16x8;
typedef __attribute__((ext_vector_type(4))) float f32x4;

__device__ __forceinline__ unsigned short f2bf(float f) {
  unsigned int u = __float_as_uint(f);
  u = (u + 0x7fffu + ((u >> 16) & 1u)) >> 16;   // round-to-nearest-even
  return (unsigned short)u;
}
__device__ __forceinline__ float bf2f(unsigned short b) {
  return __uint_as_float(((unsigned int)b) << 16);
}
__device__ __forceinline__ unsigned int pack2bf(float lo, float hi) {
  return ((unsigned int)f2bf(hi) << 16) | (unsigned int)f2bf(lo);
}

// ---------------------------------------------------------------------------
// Generic tiled SGEMM: C(M,N) = A(M,K) @ W(N,K)^T + bias(N)
// Requires M%64==0, N%64==0, K%BK==0 (true for every call here).
// 256 threads, 64x64 tile, 4x4 per-thread microtile.
// ---------------------------------------------------------------------------
template <int BK>
__global__ __launch_bounds__(256) void gemm_bias(
    const float* __restrict__ A, const float* __restrict__ W,
    const float* __restrict__ bias, float* __restrict__ C,
    int M, int N, int K)
{
  __shared__ float As[BK][68];
  __shared__ float Ws[BK][68];
  const int tid = threadIdx.x;
  const int tx = tid & 15;
  const int ty = tid >> 4;
  const int row0 = blockIdx.y * 64;
  const int col0 = blockIdx.x * 64;

  float acc[4][4] = {};

  for (int k0 = 0; k0 < K; k0 += BK) {
#pragma unroll
    for (int i = 0; i < (64 * BK) / 256; ++i) {
      int idx = tid + i * 256;
      int m = idx / BK, k = idx % BK;
      As[k][m] = A[(size_t)(row0 + m) * K + k0 + k];
      Ws[k][m] = W[(size_t)(col0 + m) * K + k0 + k];
    }
    __syncthreads();
#pragma unroll
    for (int k = 0; k < BK; ++k) {
      float a4[4], b4[4];
      *(float4*)a4 = *(const float4*)&As[k][ty * 4];
      *(float4*)b4 = *(const float4*)&Ws[k][tx * 4];
#pragma unroll
      for (int i = 0; i < 4; ++i)
#pragma unroll
        for (int j = 0; j < 4; ++j)
          acc[i][j] = fmaf(a4[i], b4[j], acc[i][j]);
    }
    __syncthreads();
  }

#pragma unroll
  for (int i = 0; i < 4; ++i) {
    int r = row0 + ty * 4 + i;
    int c = col0 + tx * 4;
    float4 o;
    o.x = acc[i][0] + bias[c + 0];
    o.y = acc[i][1] + bias[c + 1];
    o.z = acc[i][2] + bias[c + 2];
    o.w = acc[i][3] + bias[c + 3];
    *(float4*)&C[(size_t)r * N + c] = o;
  }
}

// ---------------------------------------------------------------------------
// MFMA self-attention. qkv: (B,N,3,H,32) f32. sa out: (B,N,H*32) f32.
// grid = (4 q-chunks of 80 rows, B*H). 256 threads = 4 waves.
// Per wave: one 16-row q-tile at a time.
//   scores (16x304) = 19x mfma_f32_16x16x32_bf16 (A=Q-frag, B=K-frag)
//   softmax in C-layout registers (row = 16-lane group; shfl_xor 1,2,4,8)
//   P redistributed via 1.25KB wave-private LDS chunk buffer -> A-frags
//   PV: 10 k-chunks x 2 d-tiles MFMA vs V^T
// LDS strides: row stride bytes % 16 == 0 (b128 align), <=2-way banks.
// ---------------------------------------------------------------------------
__global__ __launch_bounds__(256) void attn_mfma(
    const float* __restrict__ qkv, float* __restrict__ sa)
{
  __shared__ __align__(16) unsigned short Ksh[304 * 40];  // [j][c] stride 40
  __shared__ __align__(16) unsigned short Vt[32 * 328];   // [c][j] stride 328
  __shared__ __align__(16) unsigned short Qsh[80 * 40];   // [qr][c] stride 40
  __shared__ __align__(16) unsigned short Pw[4][16 * 40]; // per-wave P chunk

  const int bh = blockIdx.y, b = bh >> 3, h = bh & 7;
  const int chunk = blockIdx.x;          // 0..3, 80 q-rows each
  const int q0 = chunk * 80;
  const int t = threadIdx.x, wave = t >> 6, lane = t & 63;
  const int lr = lane & 15, g = lane >> 4;
  const size_t base = (size_t)b * 300 * 768 + (size_t)h * 32;
  const float scale = 0.17677669529663687f;  // 1/sqrt(32), folded into Q

  // ---- stage K rows 0..303 (zero pad rows)
  for (int i = t; i < 304 * 16; i += 256) {
    int j = i >> 4, cp = (i & 15) * 2;
    float2 v = make_float2(0.f, 0.f);
    if (j < 300) v = *(const float2*)&qkv[base + (size_t)j * 768 + 256 + cp];
    *(unsigned int*)&Ksh[j * 40 + cp] = pack2bf(v.x, v.y);
  }
  // ---- stage V^T cols 0..319 (zero pad cols)
  for (int i = t; i < 320 * 16; i += 256) {
    int j = i >> 4, cp = (i & 15) * 2;
    float2 v = make_float2(0.f, 0.f);
    if (j < 300) v = *(const float2*)&qkv[base + (size_t)j * 768 + 512 + cp];
    Vt[(size_t)cp * 328 + j] = f2bf(v.x);
    Vt[(size_t)(cp + 1) * 328 + j] = f2bf(v.y);
  }
  // ---- stage Q rows q0..q0+79 (pre-scaled, zero pad rows)
  for (int i = t; i < 80 * 16; i += 256) {
    int qr = i >> 4, cp = (i & 15) * 2;
    int q = q0 + qr;
    float2 v = make_float2(0.f, 0.f);
    if (q < 300) v = *(const float2*)&qkv[base + (size_t)q * 768 + cp];
    *(unsigned int*)&Qsh[qr * 40 + cp] = pack2bf(v.x * scale, v.y * scale);
  }
  __syncthreads();

  unsigned short* P = &Pw[wave][0];
  const int ntiles = (chunk < 3) ? 5 : 4;   // chunk 3 covers tiles 15..18

  for (int it = wave; it < ntiles; it += 4) {
    const int gt = chunk * 5 + it;          // global q-tile, 0..18

    bf16x8 aQ = *(const bf16x8*)&Qsh[(it * 16 + lr) * 40 + g * 8];

    // ---- scores: 19 K-tiles
    f32x4 s[19];
    const f32x4 zero = {0.f, 0.f, 0.f, 0.f};
#pragma unroll
    for (int kt = 0; kt < 19; ++kt) {
      bf16x8 bK = *(const bf16x8*)&Ksh[(kt * 16 + lr) * 40 + g * 8];
      s[kt] = __builtin_amdgcn_mfma_f32_16x16x32_bf16(aQ, bK, zero, 0, 0, 0);
    }
    // mask cols 300..303 (tile 18, lr>=12)
    if (lr >= 12) {
      s[18][0] = -1e30f; s[18][1] = -1e30f; s[18][2] = -1e30f; s[18][3] = -1e30f;
    }

    // ---- softmax over cols: per C-row r, in-lane over tiles, then 16-lane group
    float inv[4];
#pragma unroll
    for (int r = 0; r < 4; ++r) {
      float m = -1e30f;
#pragma unroll
      for (int kt = 0; kt < 19; ++kt) m = fmaxf(m, s[kt][r]);
#pragma unroll
      for (int o = 8; o >= 1; o >>= 1) m = fmaxf(m, __shfl_xor(m, o));
      float sum = 0.f;
#pragma unroll
      for (int kt = 0; kt < 19; ++kt) {
        float e = __expf(s[kt][r] - m);
        s[kt][r] = e;
        sum += e;
      }
#pragma unroll
      for (int o = 8; o >= 1; o >>= 1) sum += __shfl_xor(sum, o);
      inv[r] = 1.f / sum;
    }

    // ---- PV: 10 chunks of 32 j; P C-layout -> A-frag via wave-private LDS
    f32x4 o0 = {0.f, 0.f, 0.f, 0.f}, o1 = {0.f, 0.f, 0.f, 0.f};
#pragma unroll
    for (int ks = 0; ks < 10; ++ks) {
#pragma unroll
      for (int tp = 0; tp < 2; ++tp) {
        const int kt = ks * 2 + tp;
#pragma unroll
        for (int r = 0; r < 4; ++r) {
          unsigned short pv = (kt < 19) ? f2bf(s[kt][r]) : (unsigned short)0;
          P[(g * 4 + r) * 40 + tp * 16 + lr] = pv;
        }
      }
      asm volatile("s_waitcnt lgkmcnt(0)" ::: "memory");
      __builtin_amdgcn_sched_barrier(0);
      bf16x8 aP = *(const bf16x8*)&P[lr * 40 + g * 8];
      bf16x8 bV0 = *(const bf16x8*)&Vt[(size_t)lr * 328 + ks * 32 + g * 8];
      bf16x8 bV1 = *(const bf16x8*)&Vt[(size_t)(16 + lr) * 328 + ks * 32 + g * 8];
      o0 = __builtin_amdgcn_mfma_f32_16x16x32_bf16(aP, bV0, o0, 0, 0, 0);
      o1 = __builtin_amdgcn_mfma_f32_16x16x32_bf16(aP, bV1, o1, 0, 0, 0);
    }

    // ---- epilogue: scale rows by 1/sum, store
#pragma unroll
    for (int r = 0; r < 4; ++r) {
      int q = gt * 16 + g * 4 + r;
      if (q < 300) {
        float iv = inv[r];
        float* dst = &sa[((size_t)b * 300 + q) * 256 + h * 32];
        dst[lr] = o0[r] * iv;
        dst[16 + lr] = o1[r] * iv;
      }
    }
  }
}

// ---------------------------------------------------------------------------
// out = rmsnorm(a + b [clipped], w)   rows=4800, D=256, one block per row
// ---------------------------------------------------------------------------
__global__ __launch_bounds__(256) void add_rmsnorm(
    const float* __restrict__ a, const float* __restrict__ bsrc,
    const float* __restrict__ w, float* __restrict__ out, int clip)
{
  __shared__ float red[4];
  const int row = blockIdx.x, t = threadIdx.x;
  const size_t idx = (size_t)row * 256 + t;
  float v = a[idx] + bsrc[idx];
  if (clip) v = fminf(fmaxf(v, -65504.f), 65504.f);
  float s = v * v;
#pragma unroll
  for (int o = 32; o; o >>= 1) s += __shfl_xor(s, o);
  if ((t & 63) == 0) red[t >> 6] = s;
  __syncthreads();
  float tot = red[0] + red[1] + red[2] + red[3];
  out[idx] = v * rsqrtf(tot * (1.0f / 256.0f) + 1e-6f) * w[t];
}

// ---------------------------------------------------------------------------
// hid = silu(h[:, :512]) * h[:, 512:]
// ---------------------------------------------------------------------------
__global__ __launch_bounds__(256) void swiglu_k(
    const float* __restrict__ h, float* __restrict__ hid)
{
  size_t i = (size_t)blockIdx.x * 256 + threadIdx.x;  // < 4800*512
  int row = (int)(i >> 9), c = (int)(i & 511);
  float a = h[(size_t)row * 1024 + c];
  float g = h[(size_t)row * 1024 + 512 + c];
  hid[i] = a / (1.f + __expf(-a)) * g;
}

// ---------------------------------------------------------------------------
// Deformable sampling. One block per (b,n).
// ---------------------------------------------------------------------------
__global__ __launch_bounds__(256) void deform_k(
    const float* __restrict__ memory, const float* __restrict__ refp,
    const float* __restrict__ OFF, const float* __restrict__ AW,
    float* __restrict__ ca)
{
  __shared__ float locx[8][16], locy[8][16], wgt[8][16];
  const int bn = blockIdx.x, b = bn / 300, t = threadIdx.x;

  if (t < 128) {
    int h = t >> 4, p = t & 15;
    float cx = refp[(size_t)bn * 4 + 0], cy = refp[(size_t)bn * 4 + 1];
    float rw = refp[(size_t)bn * 4 + 2], rh = refp[(size_t)bn * 4 + 3];
    float ox = OFF[(size_t)bn * 256 + h * 32 + p * 2 + 0];
    float oy = OFF[(size_t)bn * 256 + h * 32 + p * 2 + 1];
    locx[h][p] = cx + ox * 0.125f * rw;
    locy[h][p] = cy + oy * 0.125f * rh;
    float av = AW[(size_t)bn * 128 + t];
    float mx = av;
#pragma unroll
    for (int o = 8; o; o >>= 1) mx = fmaxf(mx, __shfl_xor(mx, o));
    float e = __expf(av - mx);
    float ssum = e;
#pragma unroll
    for (int o = 8; o; o >>= 1) ssum += __shfl_xor(ssum, o);
    wgt[h][p] = e / ssum;
  }
  __syncthreads();

  const int h = t >> 5, hd = t & 31;
  const float* mb = memory + (size_t)b * 8500 * 256 + h * 32 + hd;
  float acc = 0.f;
#pragma unroll
  for (int p = 0; p < 16; ++p) {
    const int HWs[4] = {80, 40, 20, 10};
    const int Sts[4] = {0, 6400, 8000, 8400};
    const int li = p >> 2;
    const int Hh = HWs[li], Ww = HWs[li], st = Sts[li];
    float x = locx[h][p] * (float)Ww - 0.5f;
    float y = locy[h][p] * (float)Hh - 0.5f;
    float x0f = floorf(x), y0f = floorf(y);
    float dx = x - x0f, dy = y - y0f;
    int x0 = (int)x0f, y0 = (int)y0f;
    float awp = wgt[h][p];
#pragma unroll
    for (int cc = 0; cc < 4; ++cc) {
      int xi = x0 + (cc & 1), yi = y0 + (cc >> 1);
      float wc = ((cc & 1) ? dx : 1.f - dx) * ((cc >> 1) ? dy : 1.f - dy);
      bool valid = (xi >= 0) && (xi < Ww) && (yi >= 0) && (yi < Hh);
      int xc = xi < 0 ? 0 : (xi >= Ww ? Ww - 1 : xi);
      int yc = yi < 0 ? 0 : (yi >= Hh ? Hh - 1 : yi);
      float gv = mb[(size_t)(st + yc * Ww + xc) * 256];
      acc += gv * (valid ? wc * awp : 0.f);
    }
  }
  ca[(size_t)bn * 256 + t] = acc;
}

// ---------------------------------------------------------------------------
extern "C" void kernel_launch(void* const* d_in, const int* in_sizes, int n_in,
                              void* d_out, int out_size, void* d_ws, size_t ws_size,
                              hipStream_t stream)
{
  (void)in_sizes; (void)n_in; (void)out_size; (void)ws_size;
  const float* target  = (const float*)d_in[0];
  const float* refp    = (const float*)d_in[1];
  const float* memory  = (const float*)d_in[2];
  const float* qkv_w   = (const float*)d_in[3];
  const float* qkv_b   = (const float*)d_in[4];
  const float* out_w   = (const float*)d_in[5];
  const float* out_b   = (const float*)d_in[6];
  const float* norm1_w = (const float*)d_in[7];
  const float* off_w   = (const float*)d_in[8];
  const float* off_b   = (const float*)d_in[9];
  const float* aw_w    = (const float*)d_in[10];
  const float* aw_b    = (const float*)d_in[11];
  const float* cout_w  = (const float*)d_in[12];
  const float* cout_b  = (const float*)d_in[13];
  const float* norm2_w = (const float*)d_in[14];
  const float* w13     = (const float*)d_in[15];
  const float* w13_b   = (const float*)d_in[16];
  const float* w2      = (const float*)d_in[17];
  const float* w2_b    = (const float*)d_in[18];
  const float* norm3_w = (const float*)d_in[19];
  float* out = (float*)d_out;

  float* ws  = (float*)d_ws;
  float* QKV = ws;                     // 4800*768
  float* SA  = QKV + 4800 * 768;       // 4800*256
  float* T1  = SA  + 4800 * 256;       // 4800*256 (reused 3x)
  float* X   = T1  + 4800 * 256;       // 4800*256
  float* OF  = X   + 4800 * 256;       // 4800*256
  float* AWb = OF  + 4800 * 256;       // 4800*128
  float* CA  = AWb + 4800 * 128;       // 4800*256
  float* X2  = CA  + 4800 * 256;       // 4800*256
  float* Hb  = X2  + 4800 * 256;       // 4800*1024
  float* HID = Hb  + 4800 * 1024;      // 4800*512

  dim3 blk(256);

  // 1. qkv = target @ qkv_w^T + qkv_b    (4800 x 768, K=256)
  gemm_bias<32><<<dim3(12, 75), blk, 0, stream>>>(target, qkv_w, qkv_b, QKV, 4800, 768, 256);
  // 2. self-attention -> SA (B,N,H*32)  [MFMA]
  attn_mfma<<<dim3(4, 128), blk, 0, stream>>>(QKV, SA);
  // 3. out proj
  gemm_bias<32><<<dim3(4, 75), blk, 0, stream>>>(SA, out_w, out_b, T1, 4800, 256, 256);
  // 4. x = rmsnorm(target + T1, norm1_w)
  add_rmsnorm<<<4800, blk, 0, stream>>>(target, T1, norm1_w, X, 0);
  // 5. offsets / attention-weight GEMMs
  gemm_bias<32><<<dim3(4, 75), blk, 0, stream>>>(X, off_w, off_b, OF, 4800, 256, 256);
  gemm_bias<32><<<dim3(2, 75), blk, 0, stream>>>(X, aw_w, aw_b, AWb, 4800, 128, 256);
  // 6. deformable sampling (fuses aw softmax + loc computation)
  deform_k<<<4800, blk, 0, stream>>>(memory, refp, OF, AWb, CA);
  // 7. cross-attn out proj
  gemm_bias<32><<<dim3(4, 75), blk, 0, stream>>>(CA, cout_w, cout_b, T1, 4800, 256, 256);
  // 8. x2 = rmsnorm(x + T1, norm2_w)
  add_rmsnorm<<<4800, blk, 0, stream>>>(X, T1, norm2_w, X2, 0);
  // 9. FFN
  gemm_bias<32><<<dim3(16, 75), blk, 0, stream>>>(X2, w13, w13_b, Hb, 4800, 1024, 256);
  swiglu_k<<<9600, blk, 0, stream>>>(Hb, HID);
  gemm_bias<32><<<dim3(4, 75), blk, 0, stream>>>(HID, w2, w2_b, T1, 4800, 256, 512);
  // 10. out = rmsnorm(clip(x2 + T1), norm3_w)
  add_rmsnorm<<<4800, blk, 0, stream>>>(X2, T1, norm3_w, out, 1);
}

// Round 3
// 145.234 us; speedup vs baseline: 2.4787x; 1.8101x over previous
//
#include <hip/hip_runtime.h>
#include <cstdint>
#include <cstddef>

// Problem constants
// B=16, N=300, D=256, HEADS=8, HD=32, L=8500, TP=16, HID=512
// SPATIAL = (80,80),(40,40),(20,20),(10,10); starts 0,6400,8000,8400

typedef __attribute__((ext_vector_type(8))) short bf16x8;
typedef __attribute__((ext_vector_type(4))) float f32x4;

__device__ __forceinline__ unsigned short f2bf(float f) {
  unsigned int u = __float_as_uint(f);
  u = (u + 0x7fffu + ((u >> 16) & 1u)) >> 16;   // round-to-nearest-even
  return (unsigned short)u;
}
__device__ __forceinline__ float bf2f(unsigned short b) {
  return __uint_as_float(((unsigned int)b) << 16);
}
__device__ __forceinline__ unsigned int pack2bf(float lo, float hi) {
  return ((unsigned int)f2bf(hi) << 16) | (unsigned int)f2bf(lo);
}

// ---------------------------------------------------------------------------
// bf16 MFMA GEMM: C(M,N) = A(M,K)@W(N,K)^T + bias(N), f32 in/out, bf16 compute.
// Tile 64(M) x 128(N), BK=64. 256 threads = 4 waves; wave w owns cols
// [w*32, w*32+32) x all 64 rows: per K=32 sub-step 4 A-frags + 2 B-frags
// (6 ds_read_b128) feed 8 MFMAs. Stride-72 bf16 LDS rows: successive rows
// 4 banks apart -> <=2-way aliasing (free). Next K-tile's global loads issue
// before the MFMA cluster (latency hidden under compute).
// Requires M%64==0, N%128==0, K%64==0 (true for all 7 calls).
// ---------------------------------------------------------------------------
__global__ __launch_bounds__(256) void gemm_mfma(
    const float* __restrict__ A, const float* __restrict__ W,
    const float* __restrict__ bias, float* __restrict__ C,
    int M, int N, int K)
{
  __shared__ __align__(16) unsigned short As[64 * 72];
  __shared__ __align__(16) unsigned short Ws[128 * 72];
  const int t = threadIdx.x, wave = t >> 6, lane = t & 63;
  const int lr = lane & 15, g = lane >> 4;
  const int row0 = blockIdx.y * 64, col0 = blockIdx.x * 128;
  const int sr = t >> 4, sc = (t & 15) * 4;   // staging: row base, k-col (floats)

  float4 ra[4], rw[8];
  const float* Ab = A + (size_t)(row0 + sr) * K + sc;
  const float* Wb = W + (size_t)(col0 + sr) * K + sc;

#pragma unroll
  for (int i = 0; i < 4; ++i) ra[i] = *(const float4*)(Ab + (size_t)16 * i * K);
#pragma unroll
  for (int j = 0; j < 8; ++j) rw[j] = *(const float4*)(Wb + (size_t)16 * j * K);

  f32x4 acc[4][2] = {};

  for (int k0 = 0; k0 < K; k0 += 64) {
    __syncthreads();   // previous compute done reading LDS
#pragma unroll
    for (int i = 0; i < 4; ++i) {
      uint2 p;
      p.x = pack2bf(ra[i].x, ra[i].y);
      p.y = pack2bf(ra[i].z, ra[i].w);
      *(uint2*)&As[(sr + 16 * i) * 72 + sc] = p;
    }
#pragma unroll
    for (int j = 0; j < 8; ++j) {
      uint2 p;
      p.x = pack2bf(rw[j].x, rw[j].y);
      p.y = pack2bf(rw[j].z, rw[j].w);
      *(uint2*)&Ws[(sr + 16 * j) * 72 + sc] = p;
    }
    __syncthreads();   // staged data visible

    if (k0 + 64 < K) {  // issue next K-tile loads early; drain under MFMAs
#pragma unroll
      for (int i = 0; i < 4; ++i)
        ra[i] = *(const float4*)(Ab + (size_t)16 * i * K + k0 + 64);
#pragma unroll
      for (int j = 0; j < 8; ++j)
        rw[j] = *(const float4*)(Wb + (size_t)16 * j * K + k0 + 64);
    }

#pragma unroll
    for (int ks = 0; ks < 2; ++ks) {
      bf16x8 aA[4], bB[2];
#pragma unroll
      for (int i = 0; i < 4; ++i)
        aA[i] = *(const bf16x8*)&As[(i * 16 + lr) * 72 + ks * 32 + g * 8];
#pragma unroll
      for (int j = 0; j < 2; ++j)
        bB[j] = *(const bf16x8*)&Ws[(wave * 32 + j * 16 + lr) * 72 + ks * 32 + g * 8];
#pragma unroll
      for (int i = 0; i < 4; ++i)
#pragma unroll
        for (int j = 0; j < 2; ++j)
          acc[i][j] = __builtin_amdgcn_mfma_f32_16x16x32_bf16(aA[i], bB[j], acc[i][j], 0, 0, 0);
    }
  }

  // epilogue: C row = row0+i*16+g*4+r, col = col0+wave*32+j*16+lr
  const float b0 = bias[col0 + wave * 32 + lr];
  const float b1 = bias[col0 + wave * 32 + 16 + lr];
#pragma unroll
  for (int i = 0; i < 4; ++i) {
#pragma unroll
    for (int r = 0; r < 4; ++r) {
      const int row = row0 + i * 16 + g * 4 + r;
      float* dst = &C[(size_t)row * N + col0 + wave * 32 + lr];
      dst[0]  = acc[i][0][r] + b0;
      dst[16] = acc[i][1][r] + b1;
    }
  }
}

// ---------------------------------------------------------------------------
// MFMA self-attention. qkv: (B,N,3,H,32) f32. sa out: (B,N,H*32) f32.
// grid = (4 q-chunks of 80 rows, B*H). 256 threads = 4 waves.
// ---------------------------------------------------------------------------
__global__ __launch_bounds__(256) void attn_mfma(
    const float* __restrict__ qkv, float* __restrict__ sa)
{
  __shared__ __align__(16) unsigned short Ksh[304 * 40];  // [j][c] stride 40
  __shared__ __align__(16) unsigned short Vt[32 * 328];   // [c][j] stride 328
  __shared__ __align__(16) unsigned short Qsh[80 * 40];   // [qr][c] stride 40
  __shared__ __align__(16) unsigned short Pw[4][16 * 40]; // per-wave P chunk

  const int bh = blockIdx.y, b = bh >> 3, h = bh & 7;
  const int chunk = blockIdx.x;          // 0..3, 80 q-rows each
  const int q0 = chunk * 80;
  const int t = threadIdx.x, wave = t >> 6, lane = t & 63;
  const int lr = lane & 15, g = lane >> 4;
  const size_t base = (size_t)b * 300 * 768 + (size_t)h * 32;
  const float scale = 0.17677669529663687f;  // 1/sqrt(32), folded into Q

  for (int i = t; i < 304 * 16; i += 256) {
    int j = i >> 4, cp = (i & 15) * 2;
    float2 v = make_float2(0.f, 0.f);
    if (j < 300) v = *(const float2*)&qkv[base + (size_t)j * 768 + 256 + cp];
    *(unsigned int*)&Ksh[j * 40 + cp] = pack2bf(v.x, v.y);
  }
  for (int i = t; i < 320 * 16; i += 256) {
    int j = i >> 4, cp = (i & 15) * 2;
    float2 v = make_float2(0.f, 0.f);
    if (j < 300) v = *(const float2*)&qkv[base + (size_t)j * 768 + 512 + cp];
    Vt[(size_t)cp * 328 + j] = f2bf(v.x);
    Vt[(size_t)(cp + 1) * 328 + j] = f2bf(v.y);
  }
  for (int i = t; i < 80 * 16; i += 256) {
    int qr = i >> 4, cp = (i & 15) * 2;
    int q = q0 + qr;
    float2 v = make_float2(0.f, 0.f);
    if (q < 300) v = *(const float2*)&qkv[base + (size_t)q * 768 + cp];
    *(unsigned int*)&Qsh[qr * 40 + cp] = pack2bf(v.x * scale, v.y * scale);
  }
  __syncthreads();

  unsigned short* P = &Pw[wave][0];
  const int ntiles = (chunk < 3) ? 5 : 4;   // chunk 3 covers tiles 15..18

  for (int it = wave; it < ntiles; it += 4) {
    const int gt = chunk * 5 + it;          // global q-tile, 0..18

    bf16x8 aQ = *(const bf16x8*)&Qsh[(it * 16 + lr) * 40 + g * 8];

    f32x4 s[19];
    const f32x4 zero = {0.f, 0.f, 0.f, 0.f};
#pragma unroll
    for (int kt = 0; kt < 19; ++kt) {
      bf16x8 bK = *(const bf16x8*)&Ksh[(kt * 16 + lr) * 40 + g * 8];
      s[kt] = __builtin_amdgcn_mfma_f32_16x16x32_bf16(aQ, bK, zero, 0, 0, 0);
    }
    if (lr >= 12) {
      s[18][0] = -1e30f; s[18][1] = -1e30f; s[18][2] = -1e30f; s[18][3] = -1e30f;
    }

    float inv[4];
#pragma unroll
    for (int r = 0; r < 4; ++r) {
      float m = -1e30f;
#pragma unroll
      for (int kt = 0; kt < 19; ++kt) m = fmaxf(m, s[kt][r]);
#pragma unroll
      for (int o = 8; o >= 1; o >>= 1) m = fmaxf(m, __shfl_xor(m, o));
      float sum = 0.f;
#pragma unroll
      for (int kt = 0; kt < 19; ++kt) {
        float e = __expf(s[kt][r] - m);
        s[kt][r] = e;
        sum += e;
      }
#pragma unroll
      for (int o = 8; o >= 1; o >>= 1) sum += __shfl_xor(sum, o);
      inv[r] = 1.f / sum;
    }

    f32x4 o0 = {0.f, 0.f, 0.f, 0.f}, o1 = {0.f, 0.f, 0.f, 0.f};
#pragma unroll
    for (int ks = 0; ks < 10; ++ks) {
#pragma unroll
      for (int tp = 0; tp < 2; ++tp) {
        const int kt = ks * 2 + tp;
#pragma unroll
        for (int r = 0; r < 4; ++r) {
          unsigned short pv = (kt < 19) ? f2bf(s[kt][r]) : (unsigned short)0;
          P[(g * 4 + r) * 40 + tp * 16 + lr] = pv;
        }
      }
      asm volatile("s_waitcnt lgkmcnt(0)" ::: "memory");
      __builtin_amdgcn_sched_barrier(0);
      bf16x8 aP = *(const bf16x8*)&P[lr * 40 + g * 8];
      bf16x8 bV0 = *(const bf16x8*)&Vt[(size_t)lr * 328 + ks * 32 + g * 8];
      bf16x8 bV1 = *(const bf16x8*)&Vt[(size_t)(16 + lr) * 328 + ks * 32 + g * 8];
      o0 = __builtin_amdgcn_mfma_f32_16x16x32_bf16(aP, bV0, o0, 0, 0, 0);
      o1 = __builtin_amdgcn_mfma_f32_16x16x32_bf16(aP, bV1, o1, 0, 0, 0);
    }

#pragma unroll
    for (int r = 0; r < 4; ++r) {
      int q = gt * 16 + g * 4 + r;
      if (q < 300) {
        float iv = inv[r];
        float* dst = &sa[((size_t)b * 300 + q) * 256 + h * 32];
        dst[lr] = o0[r] * iv;
        dst[16 + lr] = o1[r] * iv;
      }
    }
  }
}

// ---------------------------------------------------------------------------
// out = rmsnorm(a + b [clipped], w)   rows=4800, D=256, one block per row
// ---------------------------------------------------------------------------
__global__ __launch_bounds__(256) void add_rmsnorm(
    const float* __restrict__ a, const float* __restrict__ bsrc,
    const float* __restrict__ w, float* __restrict__ out, int clip)
{
  __shared__ float red[4];
  const int row = blockIdx.x, t = threadIdx.x;
  const size_t idx = (size_t)row * 256 + t;
  float v = a[idx] + bsrc[idx];
  if (clip) v = fminf(fmaxf(v, -65504.f), 65504.f);
  float s = v * v;
#pragma unroll
  for (int o = 32; o; o >>= 1) s += __shfl_xor(s, o);
  if ((t & 63) == 0) red[t >> 6] = s;
  __syncthreads();
  float tot = red[0] + red[1] + red[2] + red[3];
  out[idx] = v * rsqrtf(tot * (1.0f / 256.0f) + 1e-6f) * w[t];
}

// ---------------------------------------------------------------------------
// hid = silu(h[:, :512]) * h[:, 512:]
// ---------------------------------------------------------------------------
__global__ __launch_bounds__(256) void swiglu_k(
    const float* __restrict__ h, float* __restrict__ hid)
{
  size_t i = (size_t)blockIdx.x * 256 + threadIdx.x;  // < 4800*512
  int row = (int)(i >> 9), c = (int)(i & 511);
  float a = h[(size_t)row * 1024 + c];
  float g = h[(size_t)row * 1024 + 512 + c];
  hid[i] = a / (1.f + __expf(-a)) * g;
}

// ---------------------------------------------------------------------------
// Deformable sampling. One block per (b,n).
// ---------------------------------------------------------------------------
__global__ __launch_bounds__(256) void deform_k(
    const float* __restrict__ memory, const float* __restrict__ refp,
    const float* __restrict__ OFF, const float* __restrict__ AW,
    float* __restrict__ ca)
{
  __shared__ float locx[8][16], locy[8][16], wgt[8][16];
  const int bn = blockIdx.x, b = bn / 300, t = threadIdx.x;

  if (t < 128) {
    int h = t >> 4, p = t & 15;
    float cx = refp[(size_t)bn * 4 + 0], cy = refp[(size_t)bn * 4 + 1];
    float rw = refp[(size_t)bn * 4 + 2], rh = refp[(size_t)bn * 4 + 3];
    float ox = OFF[(size_t)bn * 256 + h * 32 + p * 2 + 0];
    float oy = OFF[(size_t)bn * 256 + h * 32 + p * 2 + 1];
    locx[h][p] = cx + ox * 0.125f * rw;
    locy[h][p] = cy + oy * 0.125f * rh;
    float av = AW[(size_t)bn * 128 + t];
    float mx = av;
#pragma unroll
    for (int o = 8; o; o >>= 1) mx = fmaxf(mx, __shfl_xor(mx, o));
    float e = __expf(av - mx);
    float ssum = e;
#pragma unroll
    for (int o = 8; o; o >>= 1) ssum += __shfl_xor(ssum, o);
    wgt[h][p] = e / ssum;
  }
  __syncthreads();

  const int h = t >> 5, hd = t & 31;
  const float* mb = memory + (size_t)b * 8500 * 256 + h * 32 + hd;
  float acc = 0.f;
#pragma unroll
  for (int p = 0; p < 16; ++p) {
    const int HWs[4] = {80, 40, 20, 10};
    const int Sts[4] = {0, 6400, 8000, 8400};
    const int li = p >> 2;
    const int Hh = HWs[li], Ww = HWs[li], st = Sts[li];
    float x = locx[h][p] * (float)Ww - 0.5f;
    float y = locy[h][p] * (float)Hh - 0.5f;
    float x0f = floorf(x), y0f = floorf(y);
    float dx = x - x0f, dy = y - y0f;
    int x0 = (int)x0f, y0 = (int)y0f;
    float awp = wgt[h][p];
#pragma unroll
    for (int cc = 0; cc < 4; ++cc) {
      int xi = x0 + (cc & 1), yi = y0 + (cc >> 1);
      float wc = ((cc & 1) ? dx : 1.f - dx) * ((cc >> 1) ? dy : 1.f - dy);
      bool valid = (xi >= 0) && (xi < Ww) && (yi >= 0) && (yi < Hh);
      int xc = xi < 0 ? 0 : (xi >= Ww ? Ww - 1 : xi);
      int yc = yi < 0 ? 0 : (yi >= Hh ? Hh - 1 : yi);
      float gv = mb[(size_t)(st + yc * Ww + xc) * 256];
      acc += gv * (valid ? wc * awp : 0.f);
    }
  }
  ca[(size_t)bn * 256 + t] = acc;
}

// ---------------------------------------------------------------------------
extern "C" void kernel_launch(void* const* d_in, const int* in_sizes, int n_in,
                              void* d_out, int out_size, void* d_ws, size_t ws_size,
                              hipStream_t stream)
{
  (void)in_sizes; (void)n_in; (void)out_size; (void)ws_size;
  const float* target  = (const float*)d_in[0];
  const float* refp    = (const float*)d_in[1];
  const float* memory  = (const float*)d_in[2];
  const float* qkv_w   = (const float*)d_in[3];
  const float* qkv_b   = (const float*)d_in[4];
  const float* out_w   = (const float*)d_in[5];
  const float* out_b   = (const float*)d_in[6];
  const float* norm1_w = (const float*)d_in[7];
  const float* off_w   = (const float*)d_in[8];
  const float* off_b   = (const float*)d_in[9];
  const float* aw_w    = (const float*)d_in[10];
  const float* aw_b    = (const float*)d_in[11];
  const float* cout_w  = (const float*)d_in[12];
  const float* cout_b  = (const float*)d_in[13];
  const float* norm2_w = (const float*)d_in[14];
  const float* w13     = (const float*)d_in[15];
  const float* w13_b   = (const float*)d_in[16];
  const float* w2      = (const float*)d_in[17];
  const float* w2_b    = (const float*)d_in[18];
  const float* norm3_w = (const float*)d_in[19];
  float* out = (float*)d_out;

  float* ws  = (float*)d_ws;
  float* QKV = ws;                     // 4800*768
  float* SA  = QKV + 4800 * 768;       // 4800*256
  float* T1  = SA  + 4800 * 256;       // 4800*256 (reused 3x)
  float* X   = T1  + 4800 * 256;       // 4800*256
  float* OF  = X   + 4800 * 256;       // 4800*256
  float* AWb = OF  + 4800 * 256;       // 4800*128
  float* CA  = AWb + 4800 * 128;       // 4800*256
  float* X2  = CA  + 4800 * 256;       // 4800*256
  float* Hb  = X2  + 4800 * 256;       // 4800*1024
  float* HID = Hb  + 4800 * 1024;      // 4800*512

  dim3 blk(256);

  // 1. qkv = target @ qkv_w^T + qkv_b    (4800 x 768, K=256)
  gemm_mfma<<<dim3(6, 75), blk, 0, stream>>>(target, qkv_w, qkv_b, QKV, 4800, 768, 256);
  // 2. self-attention -> SA (B,N,H*32)  [MFMA]
  attn_mfma<<<dim3(4, 128), blk, 0, stream>>>(QKV, SA);
  // 3. out proj
  gemm_mfma<<<dim3(2, 75), blk, 0, stream>>>(SA, out_w, out_b, T1, 4800, 256, 256);
  // 4. x = rmsnorm(target + T1, norm1_w)
  add_rmsnorm<<<4800, blk, 0, stream>>>(target, T1, norm1_w, X, 0);
  // 5. offsets / attention-weight GEMMs
  gemm_mfma<<<dim3(2, 75), blk, 0, stream>>>(X, off_w, off_b, OF, 4800, 256, 256);
  gemm_mfma<<<dim3(1, 75), blk, 0, stream>>>(X, aw_w, aw_b, AWb, 4800, 128, 256);
  // 6. deformable sampling (fuses aw softmax + loc computation)
  deform_k<<<4800, blk, 0, stream>>>(memory, refp, OF, AWb, CA);
  // 7. cross-attn out proj
  gemm_mfma<<<dim3(2, 75), blk, 0, stream>>>(CA, cout_w, cout_b, T1, 4800, 256, 256);
  // 8. x2 = rmsnorm(x + T1, norm2_w)
  add_rmsnorm<<<4800, blk, 0, stream>>>(X, T1, norm2_w, X2, 0);
  // 9. FFN
  gemm_mfma<<<dim3(8, 75), blk, 0, stream>>>(X2, w13, w13_b, Hb, 4800, 1024, 256);
  swiglu_k<<<9600, blk, 0, stream>>>(Hb, HID);
  gemm_mfma<<<dim3(2, 75), blk, 0, stream>>>(HID, w2, w2_b, T1, 4800, 256, 512);
  // 10. out = rmsnorm(clip(x2 + T1), norm3_w)
  add_rmsnorm<<<4800, blk, 0, stream>>>(X2, T1, norm3_w, out, 1);
}